// Round 1
// baseline (330.757 us; speedup 1.0000x reference)
//
#include <hip/hip_runtime.h>
#include <hip/hip_bf16.h>
#include <cstdint>

typedef __bf16 bf16_t;
typedef __bf16 bf16x4 __attribute__((ext_vector_type(4)));
typedef __bf16 bf16x8 __attribute__((ext_vector_type(8)));
typedef float  f32x4  __attribute__((ext_vector_type(4)));

#define MFMA16(a,b,c) __builtin_amdgcn_mfma_f32_16x16x32_bf16(a,b,c,0,0,0)

// ---------------- f32 -> bf16 convert (vectorized, grid-stride) ----------------
__global__ void k_cvt(const float* __restrict__ src, bf16_t* __restrict__ dst, int n4){
    int stride = gridDim.x * blockDim.x;
    for (int i = blockIdx.x * blockDim.x + threadIdx.x; i < n4; i += stride){
        float4 v = ((const float4*)src)[i];
        bf16x4 o = { (bf16_t)v.x, (bf16_t)v.y, (bf16_t)v.z, (bf16_t)v.w };
        ((bf16x4*)dst)[i] = o;
    }
}

// ------------- transpose + convert: src f32 [R][C] -> dst bf16 [C][R] ----------
__global__ void k_transpose_cvt(const float* __restrict__ src, bf16_t* __restrict__ dst,
                                int R, int C){
    __shared__ bf16_t tile[32][33];
    int c0 = blockIdx.x * 32, r0 = blockIdx.y * 32;
    int tx = threadIdx.x & 31, g = threadIdx.x >> 5;   // g in [0,8)
#pragma unroll
    for (int p = 0; p < 4; ++p){
        int r = g + p * 8;
        tile[r][tx] = (bf16_t)src[(size_t)(r0 + r) * C + c0 + tx];
    }
    __syncthreads();
#pragma unroll
    for (int p = 0; p < 4; ++p){
        int rr = g + p * 8;                            // dst row = src col
        dst[(size_t)(c0 + rr) * R + r0 + tx] = tile[tx][rr];
    }
}

// ---------------- GEMM: C[M,N] = A[M,K](bf16) * Bt[N,K]^T (bf16) + bias --------
// MODE 0: qkv epilogue -> q/k/v bf16 ws [B,H,T,64] + k/v f32 into `present`
// MODE 1: plain f32 store C[m*N+n]
template<int MODE>
__global__ void k_gemm(const bf16_t* __restrict__ A, const bf16_t* __restrict__ Bt,
                       const float* __restrict__ bias,
                       float* __restrict__ Cout,      // MODE0: present base; MODE1: out
                       bf16_t* __restrict__ qkvws,    // MODE0: Qb (Kb=+4194304, Vb=+8388608)
                       int M, int N, int K){
    __shared__ bf16_t sA[128 * 32];
    __shared__ bf16_t sB[128 * 32];
    int m0 = blockIdx.x * 128, n0 = blockIdx.y * 128;
    int tid = threadIdx.x, lane = tid & 63, w = tid >> 6;
    int lr = lane & 15, lg = lane >> 4;
    int wm = (w >> 1) * 64, wn = (w & 1) * 64;
    f32x4 acc[4][4] = {};

    for (int k0 = 0; k0 < K; k0 += 32){
#pragma unroll
        for (int p = 0; p < 2; ++p){
            int c = tid + p * 256;                 // 512 chunks of 8 bf16
            int row = c >> 2, kc = (c & 3) * 8;
            *(bf16x8*)(sA + row * 32 + kc) = *(const bf16x8*)(A + (size_t)(m0 + row) * K + k0 + kc);
            *(bf16x8*)(sB + row * 32 + kc) = *(const bf16x8*)(Bt + (size_t)(n0 + row) * K + k0 + kc);
        }
        __syncthreads();
        bf16x8 af[4], bfm[4];
#pragma unroll
        for (int i = 0; i < 4; ++i){
            af[i]  = *(const bf16x8*)(sA + (wm + i * 16 + lr) * 32 + lg * 8);
            bfm[i] = *(const bf16x8*)(sB + (wn + i * 16 + lr) * 32 + lg * 8);
        }
#pragma unroll
        for (int i = 0; i < 4; ++i)
#pragma unroll
            for (int j = 0; j < 4; ++j)
                acc[i][j] = MFMA16(af[i], bfm[j], acc[i][j]);
        __syncthreads();
    }

#pragma unroll
    for (int j = 0; j < 4; ++j){
        int n = n0 + wn + j * 16 + lr;
        float bv = bias[n];
#pragma unroll
        for (int i = 0; i < 4; ++i){
            int mbase = m0 + wm + i * 16 + lg * 4;
#pragma unroll
            for (int r = 0; r < 4; ++r){
                float cv = acc[i][j][r] + bv;
                int m = mbase + r;
                if (MODE == 1){
                    Cout[(size_t)m * N + n] = cv;
                } else {
                    int b = m >> 11, t = m & 2047;
                    int sec = n >> 10, rem = n & 1023;
                    int h = rem >> 6, d = rem & 63;
                    size_t hoff = (((size_t)b * 16 + h) * 2048 + t) * 64 + d;
                    qkvws[(size_t)sec * 4194304 + hoff] = (bf16_t)cv;
                    if (sec > 0)
                        Cout[((((size_t)b * 2 + (sec - 1)) * 16 + h) * 2048 + t) * 64 + d] = cv;
                }
            }
        }
    }
}

// ---------------- flash attention: QB=64, KB=64, hd=64, 4 waves ----------------
__global__ void k_flash(const bf16_t* __restrict__ qb, const bf16_t* __restrict__ kb,
                        const bf16_t* __restrict__ vb, bf16_t* __restrict__ ctx){
    const int T = 2048;
    __shared__ bf16_t sK[64 * 72];         // [kv][d]  row-major, pad 8
    __shared__ bf16_t sV[64 * 72];         // [d][kv]  transposed, pad 8
    __shared__ bf16_t sP[4][16 * 72];      // per-wave P tile [q][kv], pad 8
    int qt = blockIdx.x, bh = blockIdx.y;
    int b = bh >> 4, h = bh & 15;
    int tid = threadIdx.x, lane = tid & 63, w = tid >> 6;
    int lr = lane & 15, lg = lane >> 4;
    int q0 = qt * 64;

    const bf16_t* qhead = qb + (size_t)bh * T * 64;
    const bf16_t* khead = kb + (size_t)bh * T * 64;
    const bf16_t* vhead = vb + (size_t)bh * T * 64;

    bf16x8 aq[2];
    {
        const bf16_t* p = qhead + (size_t)(q0 + w * 16 + lr) * 64 + lg * 8;
        aq[0] = *(const bf16x8*)(p);
        aq[1] = *(const bf16x8*)(p + 32);
    }
    float mrun[4], lrun[4];
    f32x4 oacc[4] = {};
#pragma unroll
    for (int r = 0; r < 4; ++r){ mrun[r] = -INFINITY; lrun[r] = 0.f; }

    for (int kt = 0; kt <= qt; ++kt){
        int kv0 = kt * 64;
        // stage K: row-contiguous chunks
#pragma unroll
        for (int p = 0; p < 2; ++p){
            int c = tid + p * 256;
            int row = c >> 3, dc = (c & 7) * 8;
            *(bf16x8*)(sK + row * 72 + dc) = *(const bf16x8*)(khead + (size_t)(kv0 + row) * 64 + dc);
        }
        // stage V transposed: kv-fast chunks -> conflict-light scattered b16 writes
#pragma unroll
        for (int p = 0; p < 2; ++p){
            int c = tid + p * 256;
            int kv = c & 63, dc = (c >> 6) * 8;
            bf16x8 v = *(const bf16x8*)(vhead + (size_t)(kv0 + kv) * 64 + dc);
#pragma unroll
            for (int j = 0; j < 8; ++j) sV[(dc + j) * 72 + kv] = v[j];
        }
        __syncthreads();

        // QK^T : 16 q-rows x 64 kv-cols per wave
        f32x4 s[4];
#pragma unroll
        for (int cf = 0; cf < 4; ++cf){
            f32x4 a = {};
#pragma unroll
            for (int ks = 0; ks < 2; ++ks){
                bf16x8 bk = *(const bf16x8*)(sK + (cf * 16 + lr) * 72 + ks * 32 + lg * 8);
                a = MFMA16(aq[ks], bk, a);
            }
            s[cf] = a;
        }
        // mask (strict causal: keep i>j) + scale
#pragma unroll
        for (int cf = 0; cf < 4; ++cf){
            int j = kv0 + cf * 16 + lr;
#pragma unroll
            for (int r = 0; r < 4; ++r){
                int i = q0 + w * 16 + lg * 4 + r;
                s[cf][r] = (i > j) ? s[cf][r] * 0.125f : -1e10f;
            }
        }
        // row max over 64 cols (4 frags + 16-lane xor reduce)
        float mnew[4], alpha[4], rsum[4];
#pragma unroll
        for (int r = 0; r < 4; ++r){
            float mx = fmaxf(fmaxf(s[0][r], s[1][r]), fmaxf(s[2][r], s[3][r]));
            mx = fmaxf(mx, __shfl_xor(mx, 1));
            mx = fmaxf(mx, __shfl_xor(mx, 2));
            mx = fmaxf(mx, __shfl_xor(mx, 4));
            mx = fmaxf(mx, __shfl_xor(mx, 8));
            mnew[r] = fmaxf(mrun[r], mx);
            alpha[r] = __expf(mrun[r] - mnew[r]);
            mrun[r] = mnew[r];
            rsum[r] = 0.f;
        }
        // P = exp(s - mnew) -> bf16 -> per-wave LDS (layout change C->A)
#pragma unroll
        for (int cf = 0; cf < 4; ++cf){
#pragma unroll
            for (int r = 0; r < 4; ++r){
                float pv = __expf(s[cf][r] - mnew[r]);
                rsum[r] += pv;
                sP[w][(lg * 4 + r) * 72 + cf * 16 + lr] = (bf16_t)pv;
            }
        }
#pragma unroll
        for (int r = 0; r < 4; ++r){
            float rs = rsum[r];
            rs += __shfl_xor(rs, 1);
            rs += __shfl_xor(rs, 2);
            rs += __shfl_xor(rs, 4);
            rs += __shfl_xor(rs, 8);
            lrun[r] = lrun[r] * alpha[r] + rs;
        }
#pragma unroll
        for (int df = 0; df < 4; ++df)
#pragma unroll
            for (int r = 0; r < 4; ++r)
                oacc[df][r] *= alpha[r];
        __syncthreads();
        // PV : P[16x64] x V[64x64]
#pragma unroll
        for (int ks = 0; ks < 2; ++ks){
            bf16x8 ap = *(const bf16x8*)(&sP[w][lr * 72 + ks * 32 + lg * 8]);
#pragma unroll
            for (int df = 0; df < 4; ++df){
                bf16x8 bv = *(const bf16x8*)(sV + (df * 16 + lr) * 72 + ks * 32 + lg * 8);
                oacc[df] = MFMA16(ap, bv, oacc[df]);
            }
        }
        __syncthreads();
    }
    // epilogue: ctx[b,t,h,d] bf16
#pragma unroll
    for (int df = 0; df < 4; ++df){
#pragma unroll
        for (int r = 0; r < 4; ++r){
            int t = q0 + w * 16 + lg * 4 + r;
            int d = df * 16 + lr;
            ctx[((size_t)b * 2048 + t) * 1024 + h * 64 + d] = (bf16_t)(oacc[df][r] / lrun[r]);
        }
    }
}

// -------- row 0 of each (b,h): reference softmax(all -1e10) = uniform 1/T ------
__global__ void k_row0fix(const float* __restrict__ present, bf16_t* __restrict__ ctx){
    int bh = blockIdx.x, b = bh >> 4, h = bh & 15;
    const float* v = present + ((((size_t)b * 2 + 1) * 16 + h) * 2048) * 64;
    int tid = threadIdx.x, d = tid & 63, seg = tid >> 6;
    float s = 0.f;
    for (int t = seg * 512; t < seg * 512 + 512; ++t) s += v[(size_t)t * 64 + d];
    __shared__ float red[256];
    red[tid] = s;
    __syncthreads();
    if (tid < 64){
        float tot = red[tid] + red[tid + 64] + red[tid + 128] + red[tid + 192];
        ctx[(size_t)b * 2048 * 1024 + h * 64 + tid] = (bf16_t)(tot * (1.f / 2048.f));
    }
}

extern "C" void kernel_launch(void* const* d_in, const int* in_sizes, int n_in,
                              void* d_out, int out_size, void* d_ws, size_t ws_size,
                              hipStream_t stream){
    const float* X     = (const float*)d_in[0];
    const float* Wqkv  = (const float*)d_in[1];
    const float* bqkv  = (const float*)d_in[2];
    const float* Wproj = (const float*)d_in[3];
    const float* bproj = (const float*)d_in[4];
    float* out = (float*)d_out;
    float* present = out + 4194304;

    char* ws = (char*)d_ws;
    bf16_t* Xb     = (bf16_t*)(ws);                 //  8,388,608 B
    bf16_t* WqkvT  = (bf16_t*)(ws + 8388608);       //  6,291,456 B
    bf16_t* WprojT = (bf16_t*)(ws + 14680064);      //  2,097,152 B
    bf16_t* Qb     = (bf16_t*)(ws + 16777216);      //  q/k/v bf16: 3 x 8,388,608 B
    bf16_t* CTXb   = (bf16_t*)(ws + 41943040);      //  8,388,608 B (total 50,331,648)

    k_cvt<<<2048, 256, 0, stream>>>(X, Xb, 4194304 / 4);
    k_transpose_cvt<<<dim3(3072 / 32, 1024 / 32), 256, 0, stream>>>(Wqkv, WqkvT, 1024, 3072);
    k_transpose_cvt<<<dim3(1024 / 32, 1024 / 32), 256, 0, stream>>>(Wproj, WprojT, 1024, 1024);
    k_gemm<0><<<dim3(32, 24), 256, 0, stream>>>(Xb, WqkvT, bqkv, present, Qb, 4096, 3072, 1024);
    k_flash<<<dim3(32, 32), 256, 0, stream>>>(Qb, Qb + 4194304, Qb + 8388608, CTXb);
    k_row0fix<<<32, 256, 0, stream>>>(present, CTXb);
    k_gemm<1><<<dim3(32, 8), 256, 0, stream>>>(CTXb, WprojT, bproj, out, nullptr, 4096, 1024, 1024);
}

// Round 2
// 277.586 us; speedup vs baseline: 1.1915x; 1.1915x over previous
//
#include <hip/hip_runtime.h>
#include <hip/hip_bf16.h>
#include <cstdint>

typedef __bf16 bf16_t;
typedef __bf16 bf16x4 __attribute__((ext_vector_type(4)));
typedef __bf16 bf16x8 __attribute__((ext_vector_type(8)));
typedef float  f32x4  __attribute__((ext_vector_type(4)));

#define MFMA16(a,b,c) __builtin_amdgcn_mfma_f32_16x16x32_bf16(a,b,c,0,0,0)

// async global->LDS, 16B per lane; LDS dest is wave-uniform base + lane*16
__device__ __forceinline__ void gl_lds16(const void* g, void* l){
    __builtin_amdgcn_global_load_lds(
        (const __attribute__((address_space(1))) void*)g,
        (__attribute__((address_space(3))) void*)l, 16, 0, 0);
}

// ---------------- f32 -> bf16 convert (vectorized, grid-stride) ----------------
__global__ void k_cvt(const float* __restrict__ src, bf16_t* __restrict__ dst, int n4){
    int stride = gridDim.x * blockDim.x;
    for (int i = blockIdx.x * blockDim.x + threadIdx.x; i < n4; i += stride){
        float4 v = ((const float4*)src)[i];
        bf16x4 o = { (bf16_t)v.x, (bf16_t)v.y, (bf16_t)v.z, (bf16_t)v.w };
        ((bf16x4*)dst)[i] = o;
    }
}

// ------------- transpose + convert: src f32 [R][C] -> dst bf16 [C][R] ----------
__global__ void k_transpose_cvt(const float* __restrict__ src, bf16_t* __restrict__ dst,
                                int R, int C){
    __shared__ bf16_t tile[32][33];
    int c0 = blockIdx.x * 32, r0 = blockIdx.y * 32;
    int tx = threadIdx.x & 31, g = threadIdx.x >> 5;
#pragma unroll
    for (int p = 0; p < 4; ++p){
        int r = g + p * 8;
        tile[r][tx] = (bf16_t)src[(size_t)(r0 + r) * C + c0 + tx];
    }
    __syncthreads();
#pragma unroll
    for (int p = 0; p < 4; ++p){
        int rr = g + p * 8;
        dst[(size_t)(c0 + rr) * R + r0 + tx] = tile[tx][rr];
    }
}

// ---- V transpose: present-v f32 [bh][t][64] -> Vt bf16 [bh][d][t] (swizzled) --
// swizzle: within each 64-elem t-segment, t' = t ^ ((d&7)<<3)
__global__ void k_vt(const float* __restrict__ present, bf16_t* __restrict__ vt){
    __shared__ bf16_t tile[32][33];
    int t0 = blockIdx.x * 32;         // 64 tiles over T
    int d0 = blockIdx.y * 32;         // 2 tiles over hd
    int bh = blockIdx.z;              // 32
    int b = bh >> 4, h = bh & 15;
    const float* src = present + ((((size_t)b * 2 + 1) * 16 + h) * 2048) * 64;
    int tx = threadIdx.x & 31, g = threadIdx.x >> 5;
#pragma unroll
    for (int p = 0; p < 4; ++p){
        int r = g + p * 8;            // t offset
        tile[r][tx] = (bf16_t)src[(size_t)(t0 + r) * 64 + d0 + tx];
    }
    __syncthreads();
#pragma unroll
    for (int p = 0; p < 4; ++p){
        int rr = g + p * 8;           // d offset within 32
        int d = d0 + rr;
        int t = t0 + tx;
        int tsw = (t & ~63) | ((t & 63) ^ ((d & 7) << 3));
        vt[((size_t)bh * 64 + d) * 2048 + tsw] = tile[tx][rr];
    }
}

// ---------------- GEMM: C[M,N] = A[M,K](bf16) * Bt[N,K]^T (bf16) + bias --------
// m97-style: 128x128 tile, BK=32, global_load_lds width-16 staging.
// MODE 0: qkv epilogue -> Q plain / K swizzled bf16 ws + k/v f32 into `present`
// MODE 1: plain f32 store C[m*N+n]
template<int MODE>
__global__ void k_gemm(const bf16_t* __restrict__ A, const bf16_t* __restrict__ Bt,
                       const float* __restrict__ bias,
                       float* __restrict__ Cout,      // MODE0: present base; MODE1: out
                       bf16_t* __restrict__ qws, bf16_t* __restrict__ kws,
                       int M, int N, int K){
    __shared__ bf16_t sA[128 * 32];
    __shared__ bf16_t sB[128 * 32];
    int m0 = blockIdx.x * 128, n0 = blockIdx.y * 128;
    int tid = threadIdx.x, lane = tid & 63, w = tid >> 6;
    int lr = lane & 15, lg = lane >> 4;
    int wm = (w >> 1) * 64, wn = (w & 1) * 64;
    f32x4 acc[4][4] = {};

    for (int k0 = 0; k0 < K; k0 += 32){
        // stage via global_load_lds: 8 chunks of 1KB each for A and B; wave w gets {w, w+4}
#pragma unroll
        for (int p = 0; p < 2; ++p){
            int c = w + p * 4;
            gl_lds16(A  + (size_t)(m0 + c * 16 + (lane >> 2)) * K + k0 + (lane & 3) * 8,
                     &sA[c * 512]);
            gl_lds16(Bt + (size_t)(n0 + c * 16 + (lane >> 2)) * K + k0 + (lane & 3) * 8,
                     &sB[c * 512]);
        }
        __syncthreads();
        bf16x8 af[4], bfm[4];
#pragma unroll
        for (int i = 0; i < 4; ++i){
            af[i]  = *(const bf16x8*)(sA + (wm + i * 16 + lr) * 32 + lg * 8);
            bfm[i] = *(const bf16x8*)(sB + (wn + i * 16 + lr) * 32 + lg * 8);
        }
#pragma unroll
        for (int i = 0; i < 4; ++i)
#pragma unroll
            for (int j = 0; j < 4; ++j)
                acc[i][j] = MFMA16(af[i], bfm[j], acc[i][j]);
        __syncthreads();
    }

#pragma unroll
    for (int j = 0; j < 4; ++j){
        int n = n0 + wn + j * 16 + lr;
        float bv = bias[n];
#pragma unroll
        for (int i = 0; i < 4; ++i){
            int mbase = m0 + wm + i * 16 + lg * 4;
#pragma unroll
            for (int r = 0; r < 4; ++r){
                float cv = acc[i][j][r] + bv;
                int m = mbase + r;
                if (MODE == 1){
                    Cout[(size_t)m * N + n] = cv;
                } else {
                    int b = m >> 11, t = m & 2047;
                    int sec = n >> 10, rem = n & 1023;
                    int h = rem >> 6, d = rem & 63;
                    size_t hbase = (((size_t)b * 16 + h) * 2048 + t) * 64;
                    if (sec == 0){
                        qws[hbase + d] = (bf16_t)cv;
                    } else {
                        if (sec == 1)
                            kws[hbase + (d ^ ((t & 7) << 3))] = (bf16_t)cv;
                        Cout[((((size_t)b * 2 + (sec - 1)) * 16 + h) * 2048 + t) * 64 + d] = cv;
                    }
                }
            }
        }
    }
}

// ---------------- flash attention: paired q-tiles, dbuf LDS, 1 barrier/tile ----
// qb: [bh][t][64] plain; kb: [bh][t][64] d-swizzled; vt: [bh][d][t] t-swizzled
__global__ __launch_bounds__(256, 2) void k_flash(const bf16_t* __restrict__ qb,
                        const bf16_t* __restrict__ kb, const bf16_t* __restrict__ vt,
                        bf16_t* __restrict__ ctx){
    __shared__ bf16_t sK[2][64 * 64];
    __shared__ bf16_t sV[2][64 * 64];
    __shared__ bf16_t sP[4][16 * 72];
    int pair = blockIdx.x, bh = blockIdx.y;
    int b = bh >> 4, h = bh & 15;
    int tid = threadIdx.x, lane = tid & 63, w = tid >> 6;
    int lr = lane & 15, lg = lane >> 4;
    const bf16_t* qhead = qb + (size_t)bh * 131072;
    const bf16_t* khead = kb + (size_t)bh * 131072;
    const bf16_t* vhead = vt + (size_t)bh * 131072;
    const float SC = 0.18033688f;           // 0.125 * log2(e)

    for (int half = 0; half < 2; ++half){
        int qt = half ? 31 - pair : pair;
        int q0 = qt * 64;

        bf16x8 aq0 = *(const bf16x8*)(qhead + (size_t)(q0 + w * 16 + lr) * 64 + lg * 8);
        bf16x8 aq1 = *(const bf16x8*)(qhead + (size_t)(q0 + w * 16 + lr) * 64 + 32 + lg * 8);

        float m2[4], lsum[4];
        f32x4 oacc[4] = {};
#pragma unroll
        for (int r = 0; r < 4; ++r){ m2[r] = -INFINITY; lsum[r] = 0.f; }

        // prologue stage of tile 0 into buf 0
#pragma unroll
        for (int p = 0; p < 2; ++p){
            int c = w + p * 4;
            gl_lds16(khead + (size_t)(c * 8 + (lane >> 3)) * 64 + (lane & 7) * 8, &sK[0][c * 512]);
            gl_lds16(vhead + (size_t)(c * 8 + (lane >> 3)) * 2048 + (lane & 7) * 8, &sV[0][c * 512]);
        }
        __syncthreads();

        int buf = 0;
        for (int kt = 0; kt <= qt; ++kt){
            int kv0 = kt * 64;
            if (kt < qt){                    // prefetch next tile into other buffer
                int nv0 = kv0 + 64;
#pragma unroll
                for (int p = 0; p < 2; ++p){
                    int c = w + p * 4;
                    gl_lds16(khead + (size_t)(nv0 + c * 8 + (lane >> 3)) * 64 + (lane & 7) * 8,
                             &sK[buf ^ 1][c * 512]);
                    gl_lds16(vhead + (size_t)(c * 8 + (lane >> 3)) * 2048 + nv0 + (lane & 7) * 8,
                             &sV[buf ^ 1][c * 512]);
                }
            }
            // QK^T
            f32x4 s[4];
#pragma unroll
            for (int cf = 0; cf < 4; ++cf){
                int kv = cf * 16 + lr;
                f32x4 a = {};
#pragma unroll
                for (int ks = 0; ks < 2; ++ks){
                    bf16x8 bk = *(const bf16x8*)(&sK[buf][kv * 64 + ((ks * 32 + lg * 8) ^ ((lr & 7) << 3))]);
                    a = MFMA16(ks ? aq1 : aq0, bk, a);
                }
                s[cf] = a;
            }
            // mask + scale into log2 domain
#pragma unroll
            for (int cf = 0; cf < 4; ++cf){
                int j = kv0 + cf * 16 + lr;
#pragma unroll
                for (int r = 0; r < 4; ++r){
                    int i = q0 + w * 16 + lg * 4 + r;
                    s[cf][r] = (i > j) ? s[cf][r] * SC : -1e10f;
                }
            }
            float mnew[4], alpha[4], rsum[4];
#pragma unroll
            for (int r = 0; r < 4; ++r){
                float mx = fmaxf(fmaxf(s[0][r], s[1][r]), fmaxf(s[2][r], s[3][r]));
                mx = fmaxf(mx, __shfl_xor(mx, 1));
                mx = fmaxf(mx, __shfl_xor(mx, 2));
                mx = fmaxf(mx, __shfl_xor(mx, 4));
                mx = fmaxf(mx, __shfl_xor(mx, 8));
                mnew[r] = fmaxf(m2[r], mx);
                alpha[r] = exp2f(m2[r] - mnew[r]);
                m2[r] = mnew[r];
                rsum[r] = 0.f;
            }
#pragma unroll
            for (int cf = 0; cf < 4; ++cf)
#pragma unroll
                for (int r = 0; r < 4; ++r){
                    float pv = exp2f(s[cf][r] - mnew[r]);
                    rsum[r] += pv;
                    sP[w][(lg * 4 + r) * 72 + cf * 16 + lr] = (bf16_t)pv;
                }
#pragma unroll
            for (int r = 0; r < 4; ++r){
                float rs = rsum[r];
                rs += __shfl_xor(rs, 1);
                rs += __shfl_xor(rs, 2);
                rs += __shfl_xor(rs, 4);
                rs += __shfl_xor(rs, 8);
                lsum[r] = lsum[r] * alpha[r] + rs;
            }
#pragma unroll
            for (int df = 0; df < 4; ++df)
#pragma unroll
                for (int r = 0; r < 4; ++r) oacc[df][r] *= alpha[r];
            // PV
#pragma unroll
            for (int ks = 0; ks < 2; ++ks){
                bf16x8 ap = *(const bf16x8*)(&sP[w][lr * 72 + ks * 32 + lg * 8]);
#pragma unroll
                for (int df = 0; df < 4; ++df){
                    int d = df * 16 + lr;
                    bf16x8 bv = *(const bf16x8*)(&sV[buf][d * 64 + ((ks * 32 + lg * 8) ^ ((lr & 7) << 3))]);
                    oacc[df] = MFMA16(ap, bv, oacc[df]);
                }
            }
            __syncthreads();
            buf ^= 1;
        }
        // epilogue: ctx[b,t,h,d] bf16
#pragma unroll
        for (int df = 0; df < 4; ++df){
#pragma unroll
            for (int r = 0; r < 4; ++r){
                int t = q0 + w * 16 + lg * 4 + r;
                int d = df * 16 + lr;
                ctx[((size_t)b * 2048 + t) * 1024 + h * 64 + d] = (bf16_t)(oacc[df][r] / lsum[r]);
            }
        }
    }
}

// -------- row 0 of each (b,h): reference softmax(all -1e10) = uniform 1/T ------
__global__ void k_row0fix(const float* __restrict__ present, bf16_t* __restrict__ ctx){
    int bh = blockIdx.x, b = bh >> 4, h = bh & 15;
    const float* v = present + ((((size_t)b * 2 + 1) * 16 + h) * 2048) * 64;
    int tid = threadIdx.x, d = tid & 63, seg = tid >> 6;
    float s = 0.f;
    for (int t = seg * 512; t < seg * 512 + 512; ++t) s += v[(size_t)t * 64 + d];
    __shared__ float red[256];
    red[tid] = s;
    __syncthreads();
    if (tid < 64){
        float tot = red[tid] + red[tid + 64] + red[tid + 128] + red[tid + 192];
        ctx[(size_t)b * 2048 * 1024 + h * 64 + tid] = (bf16_t)(tot * (1.f / 2048.f));
    }
}

extern "C" void kernel_launch(void* const* d_in, const int* in_sizes, int n_in,
                              void* d_out, int out_size, void* d_ws, size_t ws_size,
                              hipStream_t stream){
    const float* X     = (const float*)d_in[0];
    const float* Wqkv  = (const float*)d_in[1];
    const float* bqkv  = (const float*)d_in[2];
    const float* Wproj = (const float*)d_in[3];
    const float* bproj = (const float*)d_in[4];
    float* out = (float*)d_out;
    float* present = out + 4194304;

    char* ws = (char*)d_ws;
    bf16_t* Xb     = (bf16_t*)(ws);                 //  8,388,608 B
    bf16_t* WqkvT  = (bf16_t*)(ws + 8388608);       //  6,291,456 B
    bf16_t* WprojT = (bf16_t*)(ws + 14680064);      //  2,097,152 B
    bf16_t* Qb     = (bf16_t*)(ws + 16777216);      //  8,388,608 B (plain)
    bf16_t* Kb     = (bf16_t*)(ws + 25165824);      //  8,388,608 B (d-swizzled)
    bf16_t* Vt     = (bf16_t*)(ws + 33554432);      //  8,388,608 B ([bh][d][t] swizzled)
    bf16_t* CTXb   = (bf16_t*)(ws + 41943040);      //  8,388,608 B (total 50,331,648)

    k_cvt<<<2048, 256, 0, stream>>>(X, Xb, 4194304 / 4);
    k_transpose_cvt<<<dim3(3072 / 32, 1024 / 32), 256, 0, stream>>>(Wqkv, WqkvT, 1024, 3072);
    k_transpose_cvt<<<dim3(1024 / 32, 1024 / 32), 256, 0, stream>>>(Wproj, WprojT, 1024, 1024);
    k_gemm<0><<<dim3(32, 24), 256, 0, stream>>>(Xb, WqkvT, bqkv, present, Qb, Kb, 4096, 3072, 1024);
    k_vt<<<dim3(64, 2, 32), 256, 0, stream>>>(present, Vt);
    k_flash<<<dim3(16, 32), 256, 0, stream>>>(Qb, Kb, Vt, CTXb);
    k_row0fix<<<32, 256, 0, stream>>>(present, CTXb);
    k_gemm<1><<<dim3(32, 8), 256, 0, stream>>>(CTXb, WprojT, bproj, out, nullptr, nullptr, 4096, 1024, 1024);
}

// Round 3
// 161.224 us; speedup vs baseline: 2.0515x; 1.7217x over previous
//
#include <hip/hip_runtime.h>
#include <hip/hip_bf16.h>
#include <cstdint>

typedef __bf16 bf16_t;
typedef __bf16 bf16x4 __attribute__((ext_vector_type(4)));
typedef __bf16 bf16x8 __attribute__((ext_vector_type(8)));
typedef float  f32x4  __attribute__((ext_vector_type(4)));

#define MFMA16(a,b,c) __builtin_amdgcn_mfma_f32_16x16x32_bf16(a,b,c,0,0,0)

// async global->LDS, 16B per lane; LDS dest is wave-uniform base + lane*16
__device__ __forceinline__ void gl_lds16(const void* g, void* l){
    __builtin_amdgcn_global_load_lds(
        (const __attribute__((address_space(1))) void*)g,
        (__attribute__((address_space(3))) void*)l, 16, 0, 0);
}

// ---------------- f32 -> bf16 convert (vectorized, grid-stride) ----------------
__global__ void k_cvt(const float* __restrict__ src, bf16_t* __restrict__ dst, int n4){
    int stride = gridDim.x * blockDim.x;
    for (int i = blockIdx.x * blockDim.x + threadIdx.x; i < n4; i += stride){
        float4 v = ((const float4*)src)[i];
        bf16x4 o = { (bf16_t)v.x, (bf16_t)v.y, (bf16_t)v.z, (bf16_t)v.w };
        ((bf16x4*)dst)[i] = o;
    }
}

// ------------- transpose + convert: src f32 [R][C] -> dst bf16 [C][R] ----------
__global__ void k_transpose_cvt(const float* __restrict__ src, bf16_t* __restrict__ dst,
                                int R, int C){
    __shared__ bf16_t tile[32][33];
    int c0 = blockIdx.x * 32, r0 = blockIdx.y * 32;
    int tx = threadIdx.x & 31, g = threadIdx.x >> 5;
#pragma unroll
    for (int p = 0; p < 4; ++p){
        int r = g + p * 8;
        tile[r][tx] = (bf16_t)src[(size_t)(r0 + r) * C + c0 + tx];
    }
    __syncthreads();
#pragma unroll
    for (int p = 0; p < 4; ++p){
        int rr = g + p * 8;
        dst[(size_t)(c0 + rr) * R + r0 + tx] = tile[tx][rr];
    }
}

// ---- V transpose: present-v f32 [bh][t][64] -> Vt bf16 [bh][d][t] (swizzled) --
// swizzle: within each 64-elem t-segment, t' = t ^ ((d&7)<<3)
__global__ void k_vt(const float* __restrict__ present, bf16_t* __restrict__ vt){
    __shared__ bf16_t tile[32][33];
    int t0 = blockIdx.x * 32;         // 64 tiles over T
    int d0 = blockIdx.y * 32;         // 2 tiles over hd
    int bh = blockIdx.z;              // 32
    int b = bh >> 4, h = bh & 15;
    const float* src = present + ((((size_t)b * 2 + 1) * 16 + h) * 2048) * 64;
    int tx = threadIdx.x & 31, g = threadIdx.x >> 5;
#pragma unroll
    for (int p = 0; p < 4; ++p){
        int r = g + p * 8;            // t offset
        tile[r][tx] = (bf16_t)src[(size_t)(t0 + r) * 64 + d0 + tx];
    }
    __syncthreads();
#pragma unroll
    for (int p = 0; p < 4; ++p){
        int rr = g + p * 8;           // d offset within 32
        int d = d0 + rr;
        int t = t0 + tx;
        int tsw = (t & ~63) | ((t & 63) ^ ((d & 7) << 3));
        vt[((size_t)bh * 64 + d) * 2048 + tsw] = tile[tx][rr];
    }
}

// ---------------- GEMM: C[M,N] = A[M,K](bf16) * Bt[N,K]^T (bf16) + bias --------
// m97-style: 128x128 tile, BK=32, global_load_lds width-16 staging.
// MODE 0: qkv epilogue -> Q plain / K swizzled bf16 ws + k/v f32 into `present`
// MODE 1: plain f32 store C[m*N+n]
template<int MODE>
__global__ void k_gemm(const bf16_t* __restrict__ A, const bf16_t* __restrict__ Bt,
                       const float* __restrict__ bias,
                       float* __restrict__ Cout,      // MODE0: present base; MODE1: out
                       bf16_t* __restrict__ qws, bf16_t* __restrict__ kws,
                       int M, int N, int K){
    __shared__ bf16_t sA[128 * 32];
    __shared__ bf16_t sB[128 * 32];
    int m0 = blockIdx.x * 128, n0 = blockIdx.y * 128;
    int tid = threadIdx.x, lane = tid & 63, w = tid >> 6;
    int lr = lane & 15, lg = lane >> 4;
    int wm = (w >> 1) * 64, wn = (w & 1) * 64;
    f32x4 acc[4][4] = {};

    for (int k0 = 0; k0 < K; k0 += 32){
        // stage via global_load_lds: 8 chunks of 1KB each for A and B; wave w gets {w, w+4}
#pragma unroll
        for (int p = 0; p < 2; ++p){
            int c = w + p * 4;
            gl_lds16(A  + (size_t)(m0 + c * 16 + (lane >> 2)) * K + k0 + (lane & 3) * 8,
                     &sA[c * 512]);
            gl_lds16(Bt + (size_t)(n0 + c * 16 + (lane >> 2)) * K + k0 + (lane & 3) * 8,
                     &sB[c * 512]);
        }
        __syncthreads();
        bf16x8 af[4], bfm[4];
#pragma unroll
        for (int i = 0; i < 4; ++i){
            af[i]  = *(const bf16x8*)(sA + (wm + i * 16 + lr) * 32 + lg * 8);
            bfm[i] = *(const bf16x8*)(sB + (wn + i * 16 + lr) * 32 + lg * 8);
        }
#pragma unroll
        for (int i = 0; i < 4; ++i)
#pragma unroll
            for (int j = 0; j < 4; ++j)
                acc[i][j] = MFMA16(af[i], bfm[j], acc[i][j]);
        __syncthreads();
    }

#pragma unroll
    for (int j = 0; j < 4; ++j){
        int n = n0 + wn + j * 16 + lr;
        float bv = bias[n];
#pragma unroll
        for (int i = 0; i < 4; ++i){
            int mbase = m0 + wm + i * 16 + lg * 4;
#pragma unroll
            for (int r = 0; r < 4; ++r){
                float cv = acc[i][j][r] + bv;
                int m = mbase + r;
                if (MODE == 1){
                    Cout[(size_t)m * N + n] = cv;
                } else {
                    int b = m >> 11, t = m & 2047;
                    int sec = n >> 10, rem = n & 1023;
                    int h = rem >> 6, d = rem & 63;
                    size_t hbase = (((size_t)b * 16 + h) * 2048 + t) * 64;
                    if (sec == 0){
                        qws[hbase + d] = (bf16_t)cv;
                    } else {
                        if (sec == 1)
                            kws[hbase + (d ^ ((t & 7) << 3))] = (bf16_t)cv;
                        Cout[((((size_t)b * 2 + (sec - 1)) * 16 + h) * 2048 + t) * 64 + d] = cv;
                    }
                }
            }
        }
    }
}

// ---------------- flash attention: paired q-tiles, dbuf LDS, 1 barrier/tile ----
// qb: [bh][t][64] plain; kb: [bh][t][64] d-swizzled; vt: [bh][d][t] t-swizzled
__global__ __launch_bounds__(256, 2) void k_flash(const bf16_t* __restrict__ qb,
                        const bf16_t* __restrict__ kb, const bf16_t* __restrict__ vt,
                        bf16_t* __restrict__ ctx){
    __shared__ bf16_t sK[2][64 * 64];
    __shared__ bf16_t sV[2][64 * 64];
    __shared__ bf16_t sP[4][16 * 72];
    int pair = blockIdx.x, bh = blockIdx.y;
    int b = bh >> 4, h = bh & 15;
    int tid = threadIdx.x, lane = tid & 63, w = tid >> 6;
    int lr = lane & 15, lg = lane >> 4;
    const bf16_t* qhead = qb + (size_t)bh * 131072;
    const bf16_t* khead = kb + (size_t)bh * 131072;
    const bf16_t* vhead = vt + (size_t)bh * 131072;
    const float SC = 0.18033688f;           // 0.125 * log2(e)

    for (int half = 0; half < 2; ++half){
        int qt = half ? 31 - pair : pair;
        int q0 = qt * 64;

        bf16x8 aq0 = *(const bf16x8*)(qhead + (size_t)(q0 + w * 16 + lr) * 64 + lg * 8);
        bf16x8 aq1 = *(const bf16x8*)(qhead + (size_t)(q0 + w * 16 + lr) * 64 + 32 + lg * 8);

        float m2[4], lsum[4];
        f32x4 oacc[4] = {};
#pragma unroll
        for (int r = 0; r < 4; ++r){ m2[r] = -INFINITY; lsum[r] = 0.f; }

        // prologue stage of tile 0 into buf 0
#pragma unroll
        for (int p = 0; p < 2; ++p){
            int c = w + p * 4;
            gl_lds16(khead + (size_t)(c * 8 + (lane >> 3)) * 64 + (lane & 7) * 8, &sK[0][c * 512]);
            gl_lds16(vhead + (size_t)(c * 8 + (lane >> 3)) * 2048 + (lane & 7) * 8, &sV[0][c * 512]);
        }
        __syncthreads();

        int buf = 0;
        for (int kt = 0; kt <= qt; ++kt){
            int kv0 = kt * 64;
            if (kt < qt){                    // prefetch next tile into other buffer
                int nv0 = kv0 + 64;
#pragma unroll
                for (int p = 0; p < 2; ++p){
                    int c = w + p * 4;
                    gl_lds16(khead + (size_t)(nv0 + c * 8 + (lane >> 3)) * 64 + (lane & 7) * 8,
                             &sK[buf ^ 1][c * 512]);
                    gl_lds16(vhead + (size_t)(c * 8 + (lane >> 3)) * 2048 + nv0 + (lane & 7) * 8,
                             &sV[buf ^ 1][c * 512]);
                }
            }
            // QK^T
            f32x4 s[4];
#pragma unroll
            for (int cf = 0; cf < 4; ++cf){
                int kv = cf * 16 + lr;
                f32x4 a = {};
#pragma unroll
                for (int ks = 0; ks < 2; ++ks){
                    bf16x8 bk = *(const bf16x8*)(&sK[buf][kv * 64 + ((ks * 32 + lg * 8) ^ ((lr & 7) << 3))]);
                    a = MFMA16(ks ? aq1 : aq0, bk, a);
                }
                s[cf] = a;
            }
            // mask + scale into log2 domain
#pragma unroll
            for (int cf = 0; cf < 4; ++cf){
                int j = kv0 + cf * 16 + lr;
#pragma unroll
                for (int r = 0; r < 4; ++r){
                    int i = q0 + w * 16 + lg * 4 + r;
                    s[cf][r] = (i > j) ? s[cf][r] * SC : -1e10f;
                }
            }
            float mnew[4], alpha[4], rsum[4];
#pragma unroll
            for (int r = 0; r < 4; ++r){
                float mx = fmaxf(fmaxf(s[0][r], s[1][r]), fmaxf(s[2][r], s[3][r]));
                mx = fmaxf(mx, __shfl_xor(mx, 1));
                mx = fmaxf(mx, __shfl_xor(mx, 2));
                mx = fmaxf(mx, __shfl_xor(mx, 4));
                mx = fmaxf(mx, __shfl_xor(mx, 8));
                mnew[r] = fmaxf(m2[r], mx);
                alpha[r] = exp2f(m2[r] - mnew[r]);
                m2[r] = mnew[r];
                rsum[r] = 0.f;
            }
#pragma unroll
            for (int cf = 0; cf < 4; ++cf)
#pragma unroll
                for (int r = 0; r < 4; ++r){
                    float pv = exp2f(s[cf][r] - mnew[r]);
                    rsum[r] += pv;
                    sP[w][(lg * 4 + r) * 72 + cf * 16 + lr] = (bf16_t)pv;
                }
#pragma unroll
            for (int r = 0; r < 4; ++r){
                float rs = rsum[r];
                rs += __shfl_xor(rs, 1);
                rs += __shfl_xor(rs, 2);
                rs += __shfl_xor(rs, 4);
                rs += __shfl_xor(rs, 8);
                lsum[r] = lsum[r] * alpha[r] + rs;
            }
#pragma unroll
            for (int df = 0; df < 4; ++df)
#pragma unroll
                for (int r = 0; r < 4; ++r) oacc[df][r] *= alpha[r];
            // PV
#pragma unroll
            for (int ks = 0; ks < 2; ++ks){
                bf16x8 ap = *(const bf16x8*)(&sP[w][lr * 72 + ks * 32 + lg * 8]);
#pragma unroll
                for (int df = 0; df < 4; ++df){
                    int d = df * 16 + lr;
                    bf16x8 bv = *(const bf16x8*)(&sV[buf][d * 64 + ((ks * 32 + lg * 8) ^ ((lr & 7) << 3))]);
                    oacc[df] = MFMA16(ap, bv, oacc[df]);
                }
            }
            __syncthreads();
            buf ^= 1;
        }
        // epilogue: ctx[b,t,h,d] bf16
#pragma unroll
        for (int df = 0; df < 4; ++df){
#pragma unroll
            for (int r = 0; r < 4; ++r){
                int t = q0 + w * 16 + lg * 4 + r;
                int d = df * 16 + lr;
                ctx[((size_t)b * 2048 + t) * 1024 + h * 64 + d] = (bf16_t)(oacc[df][r] / lsum[r]);
            }
        }
    }
}

// -------- row 0 of each (b,h): reference softmax(all -1e10) = uniform 1/T ------
// mean over t of V[bh][:,d], read from Vt bf16 [bh][d][t] (t-swizzle is a
// within-group permutation -> full-t sum unaffected). One wave per (bh,d).
__global__ void k_row0fix(const bf16_t* __restrict__ vt, bf16_t* __restrict__ ctx){
    int bh = blockIdx.y;
    int b = bh >> 4, h = bh & 15;
    int lane = threadIdx.x & 63, w = threadIdx.x >> 6;
    int d = blockIdx.x * 4 + w;
    const bf16_t* row = vt + ((size_t)bh * 64 + d) * 2048;
    float s = 0.f;
#pragma unroll
    for (int k = 0; k < 4; ++k){
        bf16x8 v = *(const bf16x8*)(row + (lane + k * 64) * 8);
#pragma unroll
        for (int j = 0; j < 8; ++j) s += (float)v[j];
    }
#pragma unroll
    for (int off = 1; off < 64; off <<= 1) s += __shfl_xor(s, off);
    if (lane == 0)
        ctx[(size_t)b * 2048 * 1024 + h * 64 + d] = (bf16_t)(s * (1.f / 2048.f));
}

extern "C" void kernel_launch(void* const* d_in, const int* in_sizes, int n_in,
                              void* d_out, int out_size, void* d_ws, size_t ws_size,
                              hipStream_t stream){
    const float* X     = (const float*)d_in[0];
    const float* Wqkv  = (const float*)d_in[1];
    const float* bqkv  = (const float*)d_in[2];
    const float* Wproj = (const float*)d_in[3];
    const float* bproj = (const float*)d_in[4];
    float* out = (float*)d_out;
    float* present = out + 4194304;

    char* ws = (char*)d_ws;
    bf16_t* Xb     = (bf16_t*)(ws);                 //  8,388,608 B
    bf16_t* WqkvT  = (bf16_t*)(ws + 8388608);       //  6,291,456 B
    bf16_t* WprojT = (bf16_t*)(ws + 14680064);      //  2,097,152 B
    bf16_t* Qb     = (bf16_t*)(ws + 16777216);      //  8,388,608 B (plain)
    bf16_t* Kb     = (bf16_t*)(ws + 25165824);      //  8,388,608 B (d-swizzled)
    bf16_t* Vt     = (bf16_t*)(ws + 33554432);      //  8,388,608 B ([bh][d][t] swizzled)
    bf16_t* CTXb   = (bf16_t*)(ws + 41943040);      //  8,388,608 B (total 50,331,648)

    k_cvt<<<2048, 256, 0, stream>>>(X, Xb, 4194304 / 4);
    k_transpose_cvt<<<dim3(3072 / 32, 1024 / 32), 256, 0, stream>>>(Wqkv, WqkvT, 1024, 3072);
    k_transpose_cvt<<<dim3(1024 / 32, 1024 / 32), 256, 0, stream>>>(Wproj, WprojT, 1024, 1024);
    k_gemm<0><<<dim3(32, 24), 256, 0, stream>>>(Xb, WqkvT, bqkv, present, Qb, Kb, 4096, 3072, 1024);
    k_vt<<<dim3(64, 2, 32), 256, 0, stream>>>(present, Vt);
    k_flash<<<dim3(16, 32), 256, 0, stream>>>(Qb, Kb, Vt, CTXb);
    k_row0fix<<<dim3(16, 32), 256, 0, stream>>>(Vt, CTXb);
    k_gemm<1><<<dim3(32, 8), 256, 0, stream>>>(CTXb, WprojT, bproj, out, nullptr, nullptr, 4096, 1024, 1024);
}

// Round 4
// 140.880 us; speedup vs baseline: 2.3478x; 1.1444x over previous
//
#include <hip/hip_runtime.h>
#include <hip/hip_bf16.h>
#include <cstdint>

typedef __bf16 bf16_t;
typedef __bf16 bf16x4 __attribute__((ext_vector_type(4)));
typedef __bf16 bf16x8 __attribute__((ext_vector_type(8)));
typedef float  f32x4  __attribute__((ext_vector_type(4)));

#define MFMA16(a,b,c) __builtin_amdgcn_mfma_f32_16x16x32_bf16(a,b,c,0,0,0)

// async global->LDS, 16B per lane; LDS dest is wave-uniform base + lane*16
__device__ __forceinline__ void gl_lds16(const void* g, void* l){
    __builtin_amdgcn_global_load_lds(
        (const __attribute__((address_space(1))) void*)g,
        (__attribute__((address_space(3))) void*)l, 16, 0, 0);
}

// ---------------- f32 -> bf16 convert (vectorized, grid-stride) ----------------
__global__ void k_cvt(const float* __restrict__ src, bf16_t* __restrict__ dst, int n4){
    int stride = gridDim.x * blockDim.x;
    for (int i = blockIdx.x * blockDim.x + threadIdx.x; i < n4; i += stride){
        float4 v = ((const float4*)src)[i];
        bf16x4 o = { (bf16_t)v.x, (bf16_t)v.y, (bf16_t)v.z, (bf16_t)v.w };
        ((bf16x4*)dst)[i] = o;
    }
}

// ------------- transpose + convert: src f32 [R][C] -> dst bf16 [C][R] ----------
__global__ void k_transpose_cvt(const float* __restrict__ src, bf16_t* __restrict__ dst,
                                int R, int C){
    __shared__ bf16_t tile[32][33];
    int c0 = blockIdx.x * 32, r0 = blockIdx.y * 32;
    int tx = threadIdx.x & 31, g = threadIdx.x >> 5;
#pragma unroll
    for (int p = 0; p < 4; ++p){
        int r = g + p * 8;
        tile[r][tx] = (bf16_t)src[(size_t)(r0 + r) * C + c0 + tx];
    }
    __syncthreads();
#pragma unroll
    for (int p = 0; p < 4; ++p){
        int rr = g + p * 8;
        dst[(size_t)(c0 + rr) * R + r0 + tx] = tile[tx][rr];
    }
}

// ---- V transpose: present-v f32 [bh][t][64] -> Vt bf16 [bh][d][t] (swizzled) --
// swizzle: within each 64-elem t-segment, t' = t ^ ((d&7)<<3)
__global__ void k_vt(const float* __restrict__ present, bf16_t* __restrict__ vt){
    __shared__ bf16_t tile[32][33];
    int t0 = blockIdx.x * 32;         // 64 tiles over T
    int d0 = blockIdx.y * 32;         // 2 tiles over hd
    int bh = blockIdx.z;              // 32
    int b = bh >> 4, h = bh & 15;
    const float* src = present + ((((size_t)b * 2 + 1) * 16 + h) * 2048) * 64;
    int tx = threadIdx.x & 31, g = threadIdx.x >> 5;
#pragma unroll
    for (int p = 0; p < 4; ++p){
        int r = g + p * 8;            // t offset
        tile[r][tx] = (bf16_t)src[(size_t)(t0 + r) * 64 + d0 + tx];
    }
    __syncthreads();
#pragma unroll
    for (int p = 0; p < 4; ++p){
        int rr = g + p * 8;           // d offset within 32
        int d = d0 + rr;
        int t = t0 + tx;
        int tsw = (t & ~63) | ((t & 63) ^ ((d & 7) << 3));
        vt[((size_t)bh * 64 + d) * 2048 + tsw] = tile[tx][rr];
    }
}

// ---------------- GEMM: C[M,N] = A[M,K](bf16) * Bt[N,K]^T (bf16) + bias --------
// m97-style: 128x128 tile, BK=32, global_load_lds width-16 staging.
// MODE 0: qkv epilogue -> Q plain / K swizzled bf16 ws + k/v f32 into `present`
// MODE 1: plain f32 store C[m*N+n]
template<int MODE>
__global__ void k_gemm(const bf16_t* __restrict__ A, const bf16_t* __restrict__ Bt,
                       const float* __restrict__ bias,
                       float* __restrict__ Cout,      // MODE0: present base; MODE1: out
                       bf16_t* __restrict__ qws, bf16_t* __restrict__ kws,
                       int M, int N, int K){
    __shared__ bf16_t sA[128 * 32];
    __shared__ bf16_t sB[128 * 32];
    int m0 = blockIdx.x * 128, n0 = blockIdx.y * 128;
    int tid = threadIdx.x, lane = tid & 63, w = tid >> 6;
    int lr = lane & 15, lg = lane >> 4;
    int wm = (w >> 1) * 64, wn = (w & 1) * 64;
    f32x4 acc[4][4] = {};

    for (int k0 = 0; k0 < K; k0 += 32){
        // stage via global_load_lds: 8 chunks of 1KB each for A and B; wave w gets {w, w+4}
#pragma unroll
        for (int p = 0; p < 2; ++p){
            int c = w + p * 4;
            gl_lds16(A  + (size_t)(m0 + c * 16 + (lane >> 2)) * K + k0 + (lane & 3) * 8,
                     &sA[c * 512]);
            gl_lds16(Bt + (size_t)(n0 + c * 16 + (lane >> 2)) * K + k0 + (lane & 3) * 8,
                     &sB[c * 512]);
        }
        __syncthreads();
        bf16x8 af[4], bfm[4];
#pragma unroll
        for (int i = 0; i < 4; ++i){
            af[i]  = *(const bf16x8*)(sA + (wm + i * 16 + lr) * 32 + lg * 8);
            bfm[i] = *(const bf16x8*)(sB + (wn + i * 16 + lr) * 32 + lg * 8);
        }
#pragma unroll
        for (int i = 0; i < 4; ++i)
#pragma unroll
            for (int j = 0; j < 4; ++j)
                acc[i][j] = MFMA16(af[i], bfm[j], acc[i][j]);
        __syncthreads();
    }

#pragma unroll
    for (int j = 0; j < 4; ++j){
        int n = n0 + wn + j * 16 + lr;
        float bv = bias[n];
#pragma unroll
        for (int i = 0; i < 4; ++i){
            int mbase = m0 + wm + i * 16 + lg * 4;
#pragma unroll
            for (int r = 0; r < 4; ++r){
                float cv = acc[i][j][r] + bv;
                int m = mbase + r;
                if (MODE == 1){
                    Cout[(size_t)m * N + n] = cv;
                } else {
                    int b = m >> 11, t = m & 2047;
                    int sec = n >> 10, rem = n & 1023;
                    int h = rem >> 6, d = rem & 63;
                    size_t hbase = (((size_t)b * 16 + h) * 2048 + t) * 64;
                    if (sec == 0){
                        qws[hbase + d] = (bf16_t)cv;
                    } else {
                        if (sec == 1)
                            kws[hbase + (d ^ ((t & 7) << 3))] = (bf16_t)cv;
                        Cout[((((size_t)b * 2 + (sec - 1)) * 16 + h) * 2048 + t) * 64 + d] = cv;
                    }
                }
            }
        }
    }
}

// ---------------- flash attention: swapped QK^T, lane-local softmax ------------
// qb: [bh][t][64] plain; kb: [bh][t][64] d-swizzled; vt: [bh][d][t] t-swizzled
// 1024 blocks: one q-tile each, XCD-chunked (same-bh on one XCD), big qt first.
__global__ __launch_bounds__(256, 3) void k_flash(const bf16_t* __restrict__ qb,
                        const bf16_t* __restrict__ kb, const bf16_t* __restrict__ vt,
                        bf16_t* __restrict__ ctx){
    __shared__ bf16_t sK[2][64 * 64];
    __shared__ bf16_t sV[2][64 * 64];
    __shared__ bf16_t sP[4][16 * 72];
    int bid = blockIdx.x;
    int wid = (bid & 7) * 128 + (bid >> 3);     // XCD-chunked bijection (1024 % 8 == 0)
    int bh = wid >> 5;
    int qt = 31 - (wid & 31);                   // big tiles dispatch first
    int b = bh >> 4, h = bh & 15;
    int tid = threadIdx.x, lane = tid & 63, w = tid >> 6;
    int lr = lane & 15, lg = lane >> 4;
    int q0 = qt * 64;
    const bf16_t* qhead = qb + (size_t)bh * 131072;
    const bf16_t* khead = kb + (size_t)bh * 131072;
    const bf16_t* vhead = vt + (size_t)bh * 131072;
    const float SC = 0.18033688f;               // 0.125 * log2(e)

    // load + pre-scale this wave's 16 Q rows (scores come out in log2 domain)
    bf16x8 aq0, aq1;
    {
        const bf16_t* p = qhead + (size_t)(q0 + w * 16 + lr) * 64 + lg * 8;
        bf16x8 r0 = *(const bf16x8*)p, r1 = *(const bf16x8*)(p + 32);
#pragma unroll
        for (int j = 0; j < 8; ++j){
            aq0[j] = (bf16_t)((float)r0[j] * SC);
            aq1[j] = (bf16_t)((float)r1[j] * SC);
        }
    }
    float m2 = -INFINITY, lsum = 0.f;
    f32x4 oacc[4] = {};

    // prologue stage of tile 0 into buf 0
#pragma unroll
    for (int p = 0; p < 2; ++p){
        int c = w + p * 4;
        gl_lds16(khead + (size_t)(c * 8 + (lane >> 3)) * 64 + (lane & 7) * 8, &sK[0][c * 512]);
        gl_lds16(vhead + (size_t)(c * 8 + (lane >> 3)) * 2048 + (lane & 7) * 8, &sV[0][c * 512]);
    }
    __syncthreads();

    int buf = 0;
    for (int kt = 0; kt <= qt; ++kt){
        if (kt < qt){                           // prefetch next tile into other buffer
            int nv0 = (kt + 1) * 64;
#pragma unroll
            for (int p = 0; p < 2; ++p){
                int c = w + p * 4;
                gl_lds16(khead + (size_t)(nv0 + c * 8 + (lane >> 3)) * 64 + (lane & 7) * 8,
                         &sK[buf ^ 1][c * 512]);
                gl_lds16(vhead + (size_t)(c * 8 + (lane >> 3)) * 2048 + nv0 + (lane & 7) * 8,
                         &sV[buf ^ 1][c * 512]);
            }
        }
        // swapped QK^T: s[cf] holds scores^T rows kv=cf*16+lg*4+r, col q=lr
        f32x4 s[4];
#pragma unroll
        for (int cf = 0; cf < 4; ++cf){
            f32x4 a = {};
#pragma unroll
            for (int ks = 0; ks < 2; ++ks){
                bf16x8 ak = *(const bf16x8*)(&sK[buf][(cf * 16 + lr) * 64 + ((ks * 32 + lg * 8) ^ ((lr & 7) << 3))]);
                a = MFMA16(ak, ks ? aq1 : aq0, a);
            }
            s[cf] = a;
        }
        if (kt == qt){                          // only the diagonal tile is masked
            int qi = w * 16 + lr;
#pragma unroll
            for (int cf = 0; cf < 4; ++cf){
                int kvb = cf * 16 + lg * 4;
#pragma unroll
                for (int r = 0; r < 4; ++r)
                    if (qi <= kvb + r) s[cf][r] = -1e10f;
            }
        }
        // lane-local row max (q=lr) + 2-shfl cross-lg reduce
        float pm = s[0][0];
#pragma unroll
        for (int cf = 0; cf < 4; ++cf)
#pragma unroll
            for (int r = 0; r < 4; ++r) pm = fmaxf(pm, s[cf][r]);
        pm = fmaxf(pm, __shfl_xor(pm, 16));
        pm = fmaxf(pm, __shfl_xor(pm, 32));
        // defer-max: only rescale when some row grew by > 8 (log2 domain, P <= 256)
        if (!__all(pm - m2 <= 8.f)){
            float mnew = fmaxf(m2, pm);
            float alpha = exp2f(m2 - mnew);
            m2 = mnew;
            lsum *= alpha;
            float ar0 = __shfl(alpha, lg * 4 + 0);
            float ar1 = __shfl(alpha, lg * 4 + 1);
            float ar2 = __shfl(alpha, lg * 4 + 2);
            float ar3 = __shfl(alpha, lg * 4 + 3);
#pragma unroll
            for (int df = 0; df < 4; ++df){
                oacc[df][0] *= ar0; oacc[df][1] *= ar1;
                oacc[df][2] *= ar2; oacc[df][3] *= ar3;
            }
        }
        // P = exp2(s - m2), packed b64 writes (4 consecutive kv per lane)
        float rsum = 0.f;
#pragma unroll
        for (int cf = 0; cf < 4; ++cf){
            bf16x4 pb;
#pragma unroll
            for (int r = 0; r < 4; ++r){
                float pv = exp2f(s[cf][r] - m2);
                rsum += pv;
                pb[r] = (bf16_t)pv;
            }
            *(bf16x4*)(&sP[w][lr * 72 + cf * 16 + lg * 4]) = pb;
        }
        rsum += __shfl_xor(rsum, 16);
        rsum += __shfl_xor(rsum, 32);
        lsum += rsum;
        // PV (per-wave sP; compiler inserts lgkmcnt)
#pragma unroll
        for (int ks = 0; ks < 2; ++ks){
            bf16x8 ap = *(const bf16x8*)(&sP[w][lr * 72 + ks * 32 + lg * 8]);
#pragma unroll
            for (int df = 0; df < 4; ++df){
                bf16x8 bv = *(const bf16x8*)(&sV[buf][(df * 16 + lr) * 64 + ((ks * 32 + lg * 8) ^ ((lr & 7) << 3))]);
                oacc[df] = MFMA16(ap, bv, oacc[df]);
            }
        }
        if (kt < qt) __syncthreads();
        buf ^= 1;
    }
    // epilogue: ctx[b,t,h,d] bf16; lsum lives in lane lr=q-local -> shfl per row
    float ls0 = __shfl(lsum, lg * 4 + 0);
    float ls1 = __shfl(lsum, lg * 4 + 1);
    float ls2 = __shfl(lsum, lg * 4 + 2);
    float ls3 = __shfl(lsum, lg * 4 + 3);
#pragma unroll
    for (int df = 0; df < 4; ++df){
        int d = df * 16 + lr;
        int tb = q0 + w * 16 + lg * 4;
        size_t base = ((size_t)b * 2048 + tb) * 1024 + h * 64 + d;
        ctx[base]            = (bf16_t)(oacc[df][0] / ls0);
        ctx[base + 1024]     = (bf16_t)(oacc[df][1] / ls1);
        ctx[base + 2048]     = (bf16_t)(oacc[df][2] / ls2);
        ctx[base + 3072]     = (bf16_t)(oacc[df][3] / ls3);
    }
}

// -------- row 0 of each (b,h): reference softmax(all -1e10) = uniform 1/T ------
// mean over t of V[bh][:,d], read from Vt bf16 [bh][d][t] (t-swizzle is a
// within-group permutation -> full-t sum unaffected). One wave per (bh,d).
__global__ void k_row0fix(const bf16_t* __restrict__ vt, bf16_t* __restrict__ ctx){
    int bh = blockIdx.y;
    int b = bh >> 4, h = bh & 15;
    int lane = threadIdx.x & 63, w = threadIdx.x >> 6;
    int d = blockIdx.x * 4 + w;
    const bf16_t* row = vt + ((size_t)bh * 64 + d) * 2048;
    float s = 0.f;
#pragma unroll
    for (int k = 0; k < 4; ++k){
        bf16x8 v = *(const bf16x8*)(row + (lane + k * 64) * 8);
#pragma unroll
        for (int j = 0; j < 8; ++j) s += (float)v[j];
    }
#pragma unroll
    for (int off = 1; off < 64; off <<= 1) s += __shfl_xor(s, off);
    if (lane == 0)
        ctx[(size_t)b * 2048 * 1024 + h * 64 + d] = (bf16_t)(s * (1.f / 2048.f));
}

extern "C" void kernel_launch(void* const* d_in, const int* in_sizes, int n_in,
                              void* d_out, int out_size, void* d_ws, size_t ws_size,
                              hipStream_t stream){
    const float* X     = (const float*)d_in[0];
    const float* Wqkv  = (const float*)d_in[1];
    const float* bqkv  = (const float*)d_in[2];
    const float* Wproj = (const float*)d_in[3];
    const float* bproj = (const float*)d_in[4];
    float* out = (float*)d_out;
    float* present = out + 4194304;

    char* ws = (char*)d_ws;
    bf16_t* Xb     = (bf16_t*)(ws);                 //  8,388,608 B
    bf16_t* WqkvT  = (bf16_t*)(ws + 8388608);       //  6,291,456 B
    bf16_t* WprojT = (bf16_t*)(ws + 14680064);      //  2,097,152 B
    bf16_t* Qb     = (bf16_t*)(ws + 16777216);      //  8,388,608 B (plain)
    bf16_t* Kb     = (bf16_t*)(ws + 25165824);      //  8,388,608 B (d-swizzled)
    bf16_t* Vt     = (bf16_t*)(ws + 33554432);      //  8,388,608 B ([bh][d][t] swizzled)
    bf16_t* CTXb   = (bf16_t*)(ws + 41943040);      //  8,388,608 B (total 50,331,648)

    k_cvt<<<2048, 256, 0, stream>>>(X, Xb, 4194304 / 4);
    k_transpose_cvt<<<dim3(3072 / 32, 1024 / 32), 256, 0, stream>>>(Wqkv, WqkvT, 1024, 3072);
    k_transpose_cvt<<<dim3(1024 / 32, 1024 / 32), 256, 0, stream>>>(Wproj, WprojT, 1024, 1024);
    k_gemm<0><<<dim3(32, 24), 256, 0, stream>>>(Xb, WqkvT, bqkv, present, Qb, Kb, 4096, 3072, 1024);
    k_vt<<<dim3(64, 2, 32), 256, 0, stream>>>(present, Vt);
    k_flash<<<1024, 256, 0, stream>>>(Qb, Kb, Vt, CTXb);
    k_row0fix<<<dim3(16, 32), 256, 0, stream>>>(Vt, CTXb);
    k_gemm<1><<<dim3(32, 8), 256, 0, stream>>>(CTXb, WprojT, bproj, out, nullptr, nullptr, 4096, 1024, 1024);
}